// Round 7
// baseline (202.120 us; speedup 1.0000x reference)
//
#include <hip/hip_runtime.h>

#define B_ 4
#define C_ 256
#define CQK 64
#define N_ 4096
#define NB 128
#define ITERS (N_ / NB)  // 32
#define TS 512           // elements per 16x32 fragment tile (1 KB)

typedef _Float16 f16;
typedef __attribute__((ext_vector_type(8))) _Float16 f16x8;
typedef __attribute__((ext_vector_type(4))) _Float16 f16x4;
typedef __attribute__((ext_vector_type(4))) float f32x4;

// Fragment-tiled layouts: matrix stored as [R/16][K/32] tiles of [16][32] f16;
// a wave's fragment load = 64 lanes x 16B over one contiguous 1 KB tile.
#define TILE_OFF(l15, quad) ((l15) * 32 + (quad) * 8)

// ---------------- K1: fused transpose + Q/K/V projection ----------------
// grid: (N/64, B), 256 thr. Reads x fp32 + weights fp32 directly.
__global__ __launch_bounds__(256) void proj(
    const float* __restrict__ x, const float* __restrict__ wq,
    const float* __restrict__ bq, const float* __restrict__ wk,
    const float* __restrict__ bk, const float* __restrict__ wv,
    const float* __restrict__ bv, f16* __restrict__ QTt, f16* __restrict__ KTt,
    f16* __restrict__ Vt) {
  __shared__ float xs[64][65];   // fp32 transpose stage (one 64c chunk)
  __shared__ f16 xt[4 * 8 * TS]; // x strip tiled: [nt 4][kt 8][16 n][32 c]
  int n0 = blockIdx.x * 64;
  int b = blockIdx.y;
  int tid = threadIdx.x, lane = tid & 63, w = tid >> 6;
  int l15 = lane & 15, quad = lane >> 4;
  const float* xb = x + (size_t)b * C_ * N_;

  for (int cc = 0; cc < 4; cc++) {
#pragma unroll
    for (int i = 0; i < 16; i++)
      xs[lane][w * 16 + i] = xb[(size_t)(cc * 64 + w * 16 + i) * N_ + n0 + lane];
    __syncthreads();
    {
      int nt = w;
      f16x8 v0, v1;
#pragma unroll
      for (int j = 0; j < 8; j++) v0[j] = (f16)xs[nt * 16 + l15][quad * 16 + j];
#pragma unroll
      for (int j = 0; j < 8; j++) v1[j] = (f16)xs[nt * 16 + l15][quad * 16 + 8 + j];
      f16* dst = xt + (nt * 8 + cc * 2 + (quad >> 1)) * TS + l15 * 32 + (quad & 1) * 16;
      *(f16x8*)dst = v0;
      *(f16x8*)(dst + 8) = v1;
    }
    __syncthreads();
  }

  // wave tasks: V o-range 64w (4 ot) + (w<2 ? Q : K) o-range 32*(w&1) (2 ot)
  const float* wqk = (w < 2) ? wq : wk;
  const float* bqk = (w < 2) ? bq : bk;
  f32x4 accV[4][4];  // [ot][nt]
  f32x4 accQ[2][4];  // [ot2][nt]
#pragma unroll
  for (int ot = 0; ot < 4; ot++)
#pragma unroll
    for (int nt = 0; nt < 4; nt++) accV[ot][nt] = (f32x4){0.f, 0.f, 0.f, 0.f};
#pragma unroll
  for (int ot = 0; ot < 2; ot++)
#pragma unroll
    for (int nt = 0; nt < 4; nt++) accQ[ot][nt] = (f32x4){0.f, 0.f, 0.f, 0.f};

#pragma unroll
  for (int kt = 0; kt < 8; kt++) {
    f16x8 xf[4];
#pragma unroll
    for (int nt = 0; nt < 4; nt++)
      xf[nt] = *(const f16x8*)(xt + (nt * 8 + kt) * TS + TILE_OFF(l15, quad));
#pragma unroll
    for (int ot = 0; ot < 4; ot++) {
      const float* p = wv + (size_t)(64 * w + 16 * ot + l15) * C_ + kt * 32 + quad * 8;
      f16x8 bf;
#pragma unroll
      for (int j = 0; j < 8; j++) bf[j] = (f16)p[j];
#pragma unroll
      for (int nt = 0; nt < 4; nt++)
        accV[ot][nt] = __builtin_amdgcn_mfma_f32_16x16x32_f16(xf[nt], bf, accV[ot][nt], 0, 0, 0);
    }
#pragma unroll
    for (int ot = 0; ot < 2; ot++) {
      const float* p = wqk + (size_t)(32 * (w & 1) + 16 * ot + l15) * C_ + kt * 32 + quad * 8;
      f16x8 af;
#pragma unroll
      for (int j = 0; j < 8; j++) af[j] = (f16)p[j];
#pragma unroll
      for (int nt = 0; nt < 4; nt++)
        accQ[ot][nt] = __builtin_amdgcn_mfma_f32_16x16x32_f16(af, xf[nt], accQ[ot][nt], 0, 0, 0);
    }
  }

  // V out: D rows n = n0+16nt+4quad+r, cols c = 64w+16ot+l15.
  // Vt A-tiles [c/16][128][16 c][32 n]
  f16* vbout = Vt + (size_t)b * C_ * N_;
#pragma unroll
  for (int ot = 0; ot < 4; ot++) {
    int o = 64 * w + 16 * ot + l15;
    float bvv = bv[o];
#pragma unroll
    for (int nt = 0; nt < 4; nt++) {
      f16x4 vals;
#pragma unroll
      for (int r = 0; r < 4; r++) vals[r] = (f16)(accV[ot][nt][r] + bvv);
      *(f16x4*)(vbout + ((size_t)(4 * w + ot) * 128 + (n0 >> 5) + (nt >> 1)) * TS +
                l15 * 32 + 16 * (nt & 1) + 4 * quad) = vals;
    }
  }
  // Q/K out: D rows o = 32(w&1)+16ot2+4quad+r, cols n = n0+16nt+l15.
  // A-tiles [n/16][2][16 n][32 o]
  f16* ob = ((w < 2) ? QTt : KTt) + (size_t)b * N_ * CQK;
#pragma unroll
  for (int ot = 0; ot < 2; ot++) {
#pragma unroll
    for (int nt = 0; nt < 4; nt++) {
      f16x4 vals;
#pragma unroll
      for (int r = 0; r < 4; r++)
        vals[r] = (f16)(accQ[ot][nt][r] + bqk[32 * (w & 1) + 16 * ot + 4 * quad + r]);
      *(f16x4*)(ob + (((size_t)(n0 >> 4) + nt) * 2 + (w & 1)) * TS + l15 * 32 +
                16 * ot + 4 * quad) = vals;
    }
  }
}

// ---------------- K2: fused attention + output projection ----------------
// Each block owns out[b][:][m0..m0+31] exclusively (full n-range) -> plain
// stores, no atomics, bit-deterministic.
__global__ __launch_bounds__(256, 2) void attn(const f16* __restrict__ qt,
                                               const f16* __restrict__ kt,
                                               const f16* __restrict__ v,
                                               const float* __restrict__ wg,
                                               const float* __restrict__ bg,
                                               float* __restrict__ out) {
  // grid: (N/32 m-tiles, B); 4 waves.
  __shared__ __align__(16) f16 sPt[2][32][128];  // P^T dbuf (2x8KB); reused as O buf
  int m0 = blockIdx.x * 32;
  int b = blockIdx.y;
  int tid = threadIdx.x, lane = tid & 63, w = tid >> 6;
  int l15 = lane & 15, quad = lane >> 4;
  const f16* qtb = qt + (size_t)b * N_ * CQK;
  const f16* ktb = kt + (size_t)b * N_ * CQK;
  const f16* vb = v + (size_t)b * C_ * N_;

  f32x4 oacc[4][2];  // [ct][mt]: rows c = 64w+16ct+4quad+r, cols m = m0+16mt+l15
#pragma unroll
  for (int ct = 0; ct < 4; ct++)
#pragma unroll
    for (int mt = 0; mt < 2; mt++) oacc[ct][mt] = (f32x4){0.f, 0.f, 0.f, 0.f};

  f16x8 kf[2][2];
#pragma unroll
  for (int mt = 0; mt < 2; mt++)
#pragma unroll
    for (int ks = 0; ks < 2; ks++)
      kf[mt][ks] = *(const f16x8*)(ktb + ((size_t)((m0 >> 4) + mt) * 2 + ks) * TS +
                                   TILE_OFF(l15, quad));

  f16x8 qf[2][2];  // rows n = n0 + 32w + 16nt + l15
#pragma unroll
  for (int nt = 0; nt < 2; nt++)
#pragma unroll
    for (int ks = 0; ks < 2; ks++)
      qf[nt][ks] = *(const f16x8*)(qtb + ((size_t)(2 * w + nt) * 2 + ks) * TS +
                                   TILE_OFF(l15, quad));

  for (int it = 0; it < ITERS; it++) {
    int n0 = it * NB;
    f16x8 vfA[2][4];
#pragma unroll
    for (int ks = 0; ks < 2; ks++)
#pragma unroll
      for (int ct = 0; ct < 4; ct++)
        vfA[ks][ct] = *(const f16x8*)(vb +
                                      ((size_t)(4 * w + ct) * 128 + (n0 >> 5) + ks) * TS +
                                      TILE_OFF(l15, quad));

    char* buf = (char*)sPt[it & 1];
#pragma unroll
    for (int nt = 0; nt < 2; nt++) {
      f32x4 sacc[2];
#pragma unroll
      for (int mt = 0; mt < 2; mt++) sacc[mt] = (f32x4){0.f, 0.f, 0.f, 0.f};
#pragma unroll
      for (int ks = 0; ks < 2; ks++)
#pragma unroll
        for (int mt = 0; mt < 2; mt++)
          sacc[mt] = __builtin_amdgcn_mfma_f32_16x16x32_f16(qf[nt][ks], kf[mt][ks],
                                                            sacc[mt], 0, 0, 0);
      // P^T: row m-local = 16mt+l15 (32 rows), col n-local = 32w+16nt+4quad+r
#pragma unroll
      for (int mt = 0; mt < 2; mt++) {
        f16x4 p;
#pragma unroll
        for (int r = 0; r < 4; r++) {
          float s = sacc[mt][r];
          p[r] = (f16)(s > 0.0f ? s : (__expf(s) - 1.0f));
        }
        int row = 16 * mt + l15;
        int colb = (64 * w + 32 * nt + 8 * quad) ^ ((row & 7) << 4);
        *(f16x4*)(buf + row * 256 + colb) = p;
      }
    }
    __syncthreads();

    // O phase: O[c][m] += V[c][n] * P[n][m]
    f16x8 vfB[2][4];
    f16x8 pa[2];
#pragma unroll
    for (int mt = 0; mt < 2; mt++) {
      int row = 16 * mt + l15;
      pa[mt] = *(const f16x8*)(buf + row * 256 + ((quad * 16) ^ ((row & 7) << 4)));
    }
#pragma unroll
    for (int ks = 0; ks < 2; ks++)
#pragma unroll
      for (int ct = 0; ct < 4; ct++)
        vfB[ks][ct] = *(const f16x8*)(vb + ((size_t)(4 * w + ct) * 128 + (n0 >> 5) +
                                            2 + ks) * TS +
                                      TILE_OFF(l15, quad));
#pragma unroll
    for (int ct = 0; ct < 4; ct++)
#pragma unroll
      for (int mt = 0; mt < 2; mt++)
        oacc[ct][mt] = __builtin_amdgcn_mfma_f32_16x16x32_f16(vfA[0][ct], pa[mt],
                                                              oacc[ct][mt], 0, 0, 0);
    if (it + 1 < ITERS) {
      int nq = n0 + NB;
#pragma unroll
      for (int nt = 0; nt < 2; nt++)
#pragma unroll
        for (int ks = 0; ks < 2; ks++)
          qf[nt][ks] = *(const f16x8*)(qtb +
                                       ((size_t)((nq >> 4) + 2 * w + nt) * 2 + ks) * TS +
                                       TILE_OFF(l15, quad));
    }
#pragma unroll
    for (int mt = 0; mt < 2; mt++) {
      int row = 16 * mt + l15;
      pa[mt] = *(const f16x8*)(buf + row * 256 + ((64 + quad * 16) ^ ((row & 7) << 4)));
    }
#pragma unroll
    for (int ct = 0; ct < 4; ct++)
#pragma unroll
      for (int mt = 0; mt < 2; mt++)
        oacc[ct][mt] = __builtin_amdgcn_mfma_f32_16x16x32_f16(vfA[1][ct], pa[mt],
                                                              oacc[ct][mt], 0, 0, 0);
#pragma unroll
    for (int mt = 0; mt < 2; mt++) {
      int row = 16 * mt + l15;
      pa[mt] = *(const f16x8*)(buf + row * 256 + ((128 + quad * 16) ^ ((row & 7) << 4)));
    }
#pragma unroll
    for (int ct = 0; ct < 4; ct++)
#pragma unroll
      for (int mt = 0; mt < 2; mt++)
        oacc[ct][mt] = __builtin_amdgcn_mfma_f32_16x16x32_f16(vfB[0][ct], pa[mt],
                                                              oacc[ct][mt], 0, 0, 0);
#pragma unroll
    for (int mt = 0; mt < 2; mt++) {
      int row = 16 * mt + l15;
      pa[mt] = *(const f16x8*)(buf + row * 256 + ((192 + quad * 16) ^ ((row & 7) << 4)));
    }
#pragma unroll
    for (int ct = 0; ct < 4; ct++)
#pragma unroll
      for (int mt = 0; mt < 2; mt++)
        oacc[ct][mt] = __builtin_amdgcn_mfma_f32_16x16x32_f16(vfB[1][ct], pa[mt],
                                                              oacc[ct][mt], 0, 0, 0);
  }

  // ---- fused output projection: out[o][m] = wg . (O/N) + bg, exclusive ----
  // Stage O/N as B-frag tiles in LDS: [mt*8 + kt][16 m][32 c] = 16 KB = sPt.
  __syncthreads();
  f16* obuf = (f16*)sPt;
#pragma unroll
  for (int ct = 0; ct < 4; ct++) {
#pragma unroll
    for (int mt = 0; mt < 2; mt++) {
      f16x4 vals;
#pragma unroll
      for (int r = 0; r < 4; r++)
        vals[r] = (f16)(oacc[ct][mt][r] * (1.0f / (float)N_));
      *(f16x4*)(obuf + (mt * 8 + 2 * w + (ct >> 1)) * TS + l15 * 32 +
                16 * (ct & 1) + 4 * quad) = vals;
    }
  }
  __syncthreads();
  f32x4 accO[4][2];  // [ot][mt]: rows o = 64w+16ot+4quad+r, cols m = m0+16mt+l15
#pragma unroll
  for (int ot = 0; ot < 4; ot++)
#pragma unroll
    for (int mt = 0; mt < 2; mt++) accO[ot][mt] = (f32x4){0.f, 0.f, 0.f, 0.f};
#pragma unroll
  for (int kt = 0; kt < 8; kt++) {
    f16x8 bO[2];
#pragma unroll
    for (int mt = 0; mt < 2; mt++)
      bO[mt] = *(const f16x8*)(obuf + (mt * 8 + kt) * TS + TILE_OFF(l15, quad));
#pragma unroll
    for (int ot = 0; ot < 4; ot++) {
      const float* p = wg + (size_t)(64 * w + 16 * ot + l15) * C_ + kt * 32 + quad * 8;
      f16x8 af;
#pragma unroll
      for (int j = 0; j < 8; j++) af[j] = (f16)p[j];
#pragma unroll
      for (int mt = 0; mt < 2; mt++)
        accO[ot][mt] = __builtin_amdgcn_mfma_f32_16x16x32_f16(af, bO[mt], accO[ot][mt], 0, 0, 0);
    }
  }
  float* outb = out + (size_t)b * C_ * N_;
#pragma unroll
  for (int ot = 0; ot < 4; ot++) {
#pragma unroll
    for (int mt = 0; mt < 2; mt++) {
      int m = m0 + 16 * mt + l15;
#pragma unroll
      for (int r = 0; r < 4; r++) {
        int o = 64 * w + 16 * ot + 4 * quad + r;
        outb[(size_t)o * N_ + m] = accO[ot][mt][r] + bg[o];
      }
    }
  }
}

extern "C" void kernel_launch(void* const* d_in, const int* in_sizes, int n_in,
                              void* d_out, int out_size, void* d_ws, size_t ws_size,
                              hipStream_t stream) {
  const float* x = (const float*)d_in[0];
  const float* wq = (const float*)d_in[1];
  const float* bq = (const float*)d_in[2];
  const float* wk = (const float*)d_in[3];
  const float* bk = (const float*)d_in[4];
  const float* wv = (const float*)d_in[5];
  const float* bv = (const float*)d_in[6];
  const float* wg = (const float*)d_in[7];
  const float* bg = (const float*)d_in[8];
  float* out = (float*)d_out;

  char* ws = (char*)d_ws;
  f16* QTt = (f16*)ws; ws += (size_t)B_ * N_ * CQK * sizeof(f16);  // 2.1 MB
  f16* KTt = (f16*)ws; ws += (size_t)B_ * N_ * CQK * sizeof(f16);  // 2.1 MB
  f16* Vt  = (f16*)ws; ws += (size_t)B_ * C_ * N_ * sizeof(f16);   // 8.4 MB

  proj<<<dim3(N_ / 64, B_), 256, 0, stream>>>(x, wq, bq, wk, bk, wv, bv,
                                              QTt, KTt, Vt);
  attn<<<dim3(N_ / 32, B_), 256, 0, stream>>>(QTt, KTt, Vt, wg, bg, out);
}

// Round 8
// 161.175 us; speedup vs baseline: 1.2540x; 1.2540x over previous
//
#include <hip/hip_runtime.h>

#define B_ 4
#define C_ 256
#define CQK 64
#define N_ 4096
#define SEG 2
#define SEGN (N_ / SEG)    // 2048
#define NB 128
#define ITERS (SEGN / NB)  // 16
#define TS 512             // elements per 16x32 fragment tile (1 KB)

typedef _Float16 f16;
typedef __attribute__((ext_vector_type(8))) _Float16 f16x8;
typedef __attribute__((ext_vector_type(4))) _Float16 f16x4;
typedef __attribute__((ext_vector_type(4))) float f32x4;
typedef __attribute__((ext_vector_type(4))) float float4v;

// Fragment-tiled layouts: matrix [R][K] stored as [R/16][K/32] tiles of
// [16][32] f16; wave fragment load = 64 lanes x 16 B over one 1 KB tile.
#define TILE_OFF(l15, quad) ((l15) * 32 + (quad) * 8)

// ---------------- K0: weights fp32 -> fragment-tiled f16 ----------------
__global__ __launch_bounds__(256) void prep_w(
    const float* __restrict__ wq, const float* __restrict__ wk,
    const float* __restrict__ wv, const float* __restrict__ wg,
    f16* __restrict__ WQt, f16* __restrict__ WKt, f16* __restrict__ WVt,
    f16* __restrict__ WGt) {
  // 20480 chunks of 8 elements; grid 80 x 256.
  int chunk = blockIdx.x * 256 + threadIdx.x;
  if (chunk >= 20480) return;
  const float* src;
  f16* dst;
  int lo;
  if (chunk < 2048) { src = wq; dst = WQt; lo = chunk * 8; }
  else if (chunk < 4096) { src = wk; dst = WKt; lo = (chunk - 2048) * 8; }
  else if (chunk < 12288) { src = wv; dst = WVt; lo = (chunk - 4096) * 8; }
  else { src = wg; dst = WGt; lo = (chunk - 12288) * 8; }
  int o = lo >> 8, k = lo & 255;
  f16x8 v;
#pragma unroll
  for (int j = 0; j < 8; j++) v[j] = (f16)src[lo + j];
  *(f16x8*)(dst + ((size_t)(o >> 4) * 8 + (k >> 5)) * TS + (o & 15) * 32 + (k & 31)) = v;
}

// ---------------- K1: fused transpose + Q/K/V projection ----------------
// grid: (N/64, B), 512 thr (8 waves). 24 output-tile tasks (V:16,Q:4,K:4),
// 3 per wave -> balanced 96 MFMA/wave.
__global__ __launch_bounds__(512) void proj(
    const float* __restrict__ x, const f16* __restrict__ WQt,
    const f16* __restrict__ WKt, const f16* __restrict__ WVt,
    const float* __restrict__ bq, const float* __restrict__ bk,
    const float* __restrict__ bv, f16* __restrict__ QTt, f16* __restrict__ KTt,
    f16* __restrict__ Vt) {
  __shared__ float xs[64][65];    // fp32 transpose stage (64n x 64c chunk)
  __shared__ f16 xt[4 * 8 * TS];  // x strip tiled: [nt 4][kt 8][16 n][32 c]
  int n0 = blockIdx.x * 64;
  int b = blockIdx.y;
  int tid = threadIdx.x, lane = tid & 63, w = tid >> 6;  // w 0..7
  int l15 = lane & 15, quad = lane >> 4;
  const float* xb = x + (size_t)b * C_ * N_;

  for (int cc = 0; cc < 4; cc++) {
#pragma unroll
    for (int i = 0; i < 8; i++)
      xs[lane][w * 8 + i] = xb[(size_t)(cc * 64 + w * 8 + i) * N_ + n0 + lane];
    __syncthreads();
    {
      int nt = w >> 1;
      f16x8 v;
#pragma unroll
      for (int j = 0; j < 8; j++)
        v[j] = (f16)xs[nt * 16 + l15][32 * (w & 1) + quad * 8 + j];
      *(f16x8*)(xt + (nt * 8 + cc * 2 + (w & 1)) * TS + l15 * 32 + quad * 8) = v;
    }
    __syncthreads();
  }

  f32x4 acc[3][4];  // [task j][nt]
#pragma unroll
  for (int j = 0; j < 3; j++)
#pragma unroll
    for (int nt = 0; nt < 4; nt++) acc[j][nt] = (f32x4){0.f, 0.f, 0.f, 0.f};

#pragma unroll
  for (int kt = 0; kt < 8; kt++) {
    f16x8 xf[4];
#pragma unroll
    for (int nt = 0; nt < 4; nt++)
      xf[nt] = *(const f16x8*)(xt + (nt * 8 + kt) * TS + TILE_OFF(l15, quad));
#pragma unroll
    for (int j = 0; j < 3; j++) {
      int g = w * 3 + j;  // wave-uniform
      const f16* Wt;
      int ot;
      bool isV = g < 16;
      if (isV) { Wt = WVt; ot = g; }
      else if (g < 20) { Wt = WQt; ot = g - 16; }
      else { Wt = WKt; ot = g - 20; }
      f16x8 wf = *(const f16x8*)(Wt + ((size_t)ot * 8 + kt) * TS + TILE_OFF(l15, quad));
#pragma unroll
      for (int nt = 0; nt < 4; nt++)
        acc[j][nt] = isV
            ? __builtin_amdgcn_mfma_f32_16x16x32_f16(xf[nt], wf, acc[j][nt], 0, 0, 0)
            : __builtin_amdgcn_mfma_f32_16x16x32_f16(wf, xf[nt], acc[j][nt], 0, 0, 0);
    }
  }

  f16* vbout = Vt + (size_t)b * C_ * N_;
#pragma unroll
  for (int j = 0; j < 3; j++) {
    int g = w * 3 + j;
    if (g < 16) {
      // V: D rows n = n0+16nt+4quad+r, cols c = 16g+l15 -> A-tiles [c/16][n/32]
      float bvv = bv[16 * g + l15];
#pragma unroll
      for (int nt = 0; nt < 4; nt++) {
        f16x4 vals;
#pragma unroll
        for (int r = 0; r < 4; r++) vals[r] = (f16)(acc[j][nt][r] + bvv);
        *(f16x4*)(vbout + ((size_t)g * 128 + (n0 >> 5) + (nt >> 1)) * TS +
                  l15 * 32 + 16 * (nt & 1) + 4 * quad) = vals;
      }
    } else {
      // Q/K: D rows o = 16oq+4quad+r, cols n = n0+16nt+l15 -> A-tiles [n/16][2]
      int oq = (g < 20) ? (g - 16) : (g - 20);
      const float* bias = (g < 20) ? bq : bk;
      f16* ob = ((g < 20) ? QTt : KTt) + (size_t)b * N_ * CQK;
#pragma unroll
      for (int nt = 0; nt < 4; nt++) {
        f16x4 vals;
#pragma unroll
        for (int r = 0; r < 4; r++)
          vals[r] = (f16)(acc[j][nt][r] + bias[16 * oq + 4 * quad + r]);
        *(f16x4*)(ob + (((size_t)(n0 >> 4) + nt) * 2 + (oq >> 1)) * TS + l15 * 32 +
                  16 * (oq & 1) + 4 * quad) = vals;
      }
    }
  }
}

// ---------------- K2: fused attention + wg projection (per-seg partial) ----
__global__ __launch_bounds__(256, 2) void attn(const f16* __restrict__ qt,
                                               const f16* __restrict__ kt,
                                               const f16* __restrict__ v,
                                               const f16* __restrict__ WGt,
                                               float* __restrict__ part) {
  // grid: (N/64 m-tiles, SEG, B); 4 waves. r5 core (63 us) + fused epilogue.
  __shared__ __align__(16) f16 sPt[2][64][128];  // P^T dbuf (32 KB); reused as O buf
  int m0 = blockIdx.x * 64;
  int seg = blockIdx.y;
  int b = blockIdx.z;
  int tid = threadIdx.x, lane = tid & 63, w = tid >> 6;
  int l15 = lane & 15, quad = lane >> 4;
  const f16* qtb = qt + (size_t)b * N_ * CQK;
  const f16* ktb = kt + (size_t)b * N_ * CQK;
  const f16* vb = v + (size_t)b * C_ * N_;

  f32x4 oacc[4][4];
#pragma unroll
  for (int ct = 0; ct < 4; ct++)
#pragma unroll
    for (int mt = 0; mt < 4; mt++) oacc[ct][mt] = (f32x4){0.f, 0.f, 0.f, 0.f};

  f16x8 kf[4][2];
#pragma unroll
  for (int mt = 0; mt < 4; mt++)
#pragma unroll
    for (int ks = 0; ks < 2; ks++)
      kf[mt][ks] = *(const f16x8*)(ktb + ((size_t)((m0 >> 4) + mt) * 2 + ks) * TS +
                                   TILE_OFF(l15, quad));

  f16x8 qf[2][2];
  {
    int nq = seg * SEGN;
#pragma unroll
    for (int nt = 0; nt < 2; nt++)
#pragma unroll
      for (int ks = 0; ks < 2; ks++)
        qf[nt][ks] = *(const f16x8*)(qtb +
                                     ((size_t)((nq >> 4) + 2 * w + nt) * 2 + ks) * TS +
                                     TILE_OFF(l15, quad));
  }

  for (int it = 0; it < ITERS; it++) {
    int n0 = seg * SEGN + it * NB;
    f16x8 vfA[2][4];
#pragma unroll
    for (int ks = 0; ks < 2; ks++)
#pragma unroll
      for (int ct = 0; ct < 4; ct++)
        vfA[ks][ct] = *(const f16x8*)(vb +
                                      ((size_t)(4 * w + ct) * 128 + (n0 >> 5) + ks) * TS +
                                      TILE_OFF(l15, quad));

    char* buf = (char*)sPt[it & 1];
#pragma unroll
    for (int nt = 0; nt < 2; nt++) {
      f32x4 sacc[4];
#pragma unroll
      for (int mt = 0; mt < 4; mt++) sacc[mt] = (f32x4){0.f, 0.f, 0.f, 0.f};
#pragma unroll
      for (int ks = 0; ks < 2; ks++)
#pragma unroll
        for (int mt = 0; mt < 4; mt++)
          sacc[mt] = __builtin_amdgcn_mfma_f32_16x16x32_f16(qf[nt][ks], kf[mt][ks],
                                                            sacc[mt], 0, 0, 0);
#pragma unroll
      for (int mt = 0; mt < 4; mt++) {
        f16x4 p;
#pragma unroll
        for (int r = 0; r < 4; r++) {
          float s = sacc[mt][r];
          p[r] = (f16)(s > 0.0f ? s : (__expf(s) - 1.0f));
        }
        int row = 16 * mt + l15;
        int colb = (64 * w + 32 * nt + 8 * quad) ^ ((row & 7) << 4);
        *(f16x4*)(buf + row * 256 + colb) = p;
      }
    }
    __syncthreads();

    f16x8 vfB[2][4];
    f16x8 pa[4];
#pragma unroll
    for (int mt = 0; mt < 4; mt++) {
      int row = 16 * mt + l15;
      pa[mt] = *(const f16x8*)(buf + row * 256 + ((quad * 16) ^ ((row & 7) << 4)));
    }
#pragma unroll
    for (int ks = 0; ks < 2; ks++)
#pragma unroll
      for (int ct = 0; ct < 4; ct++)
        vfB[ks][ct] = *(const f16x8*)(vb + ((size_t)(4 * w + ct) * 128 + (n0 >> 5) +
                                            2 + ks) * TS +
                                      TILE_OFF(l15, quad));
#pragma unroll
    for (int ct = 0; ct < 4; ct++)
#pragma unroll
      for (int mt = 0; mt < 4; mt++)
        oacc[ct][mt] = __builtin_amdgcn_mfma_f32_16x16x32_f16(vfA[0][ct], pa[mt],
                                                              oacc[ct][mt], 0, 0, 0);
    if (it + 1 < ITERS) {
      int nq = n0 + NB;
#pragma unroll
      for (int nt = 0; nt < 2; nt++)
#pragma unroll
        for (int ks = 0; ks < 2; ks++)
          qf[nt][ks] = *(const f16x8*)(qtb +
                                       ((size_t)((nq >> 4) + 2 * w + nt) * 2 + ks) * TS +
                                       TILE_OFF(l15, quad));
    }
#pragma unroll
    for (int mt = 0; mt < 4; mt++) {
      int row = 16 * mt + l15;
      pa[mt] = *(const f16x8*)(buf + row * 256 + ((64 + quad * 16) ^ ((row & 7) << 4)));
    }
#pragma unroll
    for (int ct = 0; ct < 4; ct++)
#pragma unroll
      for (int mt = 0; mt < 4; mt++)
        oacc[ct][mt] = __builtin_amdgcn_mfma_f32_16x16x32_f16(vfA[1][ct], pa[mt],
                                                              oacc[ct][mt], 0, 0, 0);
#pragma unroll
    for (int mt = 0; mt < 4; mt++) {
      int row = 16 * mt + l15;
      pa[mt] = *(const f16x8*)(buf + row * 256 + ((128 + quad * 16) ^ ((row & 7) << 4)));
    }
#pragma unroll
    for (int ct = 0; ct < 4; ct++)
#pragma unroll
      for (int mt = 0; mt < 4; mt++)
        oacc[ct][mt] = __builtin_amdgcn_mfma_f32_16x16x32_f16(vfB[0][ct], pa[mt],
                                                              oacc[ct][mt], 0, 0, 0);
#pragma unroll
    for (int mt = 0; mt < 4; mt++) {
      int row = 16 * mt + l15;
      pa[mt] = *(const f16x8*)(buf + row * 256 + ((192 + quad * 16) ^ ((row & 7) << 4)));
    }
#pragma unroll
    for (int ct = 0; ct < 4; ct++)
#pragma unroll
      for (int mt = 0; mt < 4; mt++)
        oacc[ct][mt] = __builtin_amdgcn_mfma_f32_16x16x32_f16(vfB[1][ct], pa[mt],
                                                              oacc[ct][mt], 0, 0, 0);
  }

  // ---- fused wg projection: part[seg] = wg . (O/N), exclusive stores ----
  // Stage O/N as B-frag tiles in LDS: [mt*8 + kt][16 m][32 c] = 32 KB = sPt.
  __syncthreads();
  f16* obuf = (f16*)sPt;
#pragma unroll
  for (int ct = 0; ct < 4; ct++) {
#pragma unroll
    for (int mt = 0; mt < 4; mt++) {
      f16x4 vals;
#pragma unroll
      for (int r = 0; r < 4; r++)
        vals[r] = (f16)(oacc[ct][mt][r] * (1.0f / (float)N_));
      *(f16x4*)(obuf + (mt * 8 + 2 * w + (ct >> 1)) * TS + l15 * 32 +
                16 * (ct & 1) + 4 * quad) = vals;
    }
  }
  __syncthreads();
  f32x4 accO[4][4];  // [ot][mt]: rows o = 64w+16ot+4quad+r, cols m = m0+16mt+l15
#pragma unroll
  for (int ot = 0; ot < 4; ot++)
#pragma unroll
    for (int mt = 0; mt < 4; mt++) accO[ot][mt] = (f32x4){0.f, 0.f, 0.f, 0.f};
#pragma unroll
  for (int kt = 0; kt < 8; kt++) {
    f16x8 bO[4];
#pragma unroll
    for (int mt = 0; mt < 4; mt++)
      bO[mt] = *(const f16x8*)(obuf + (mt * 8 + kt) * TS + TILE_OFF(l15, quad));
#pragma unroll
    for (int ot = 0; ot < 4; ot++) {
      f16x8 af = *(const f16x8*)(WGt + ((size_t)(4 * w + ot) * 8 + kt) * TS +
                                 TILE_OFF(l15, quad));
#pragma unroll
      for (int mt = 0; mt < 4; mt++)
        accO[ot][mt] = __builtin_amdgcn_mfma_f32_16x16x32_f16(af, bO[mt], accO[ot][mt], 0, 0, 0);
    }
  }
  float* pb = part + ((size_t)(seg * B_ + b) * C_) * N_;
#pragma unroll
  for (int ot = 0; ot < 4; ot++) {
#pragma unroll
    for (int mt = 0; mt < 4; mt++) {
      int m = m0 + 16 * mt + l15;
#pragma unroll
      for (int r = 0; r < 4; r++) {
        int o = 64 * w + 16 * ot + 4 * quad + r;
        pb[(size_t)o * N_ + m] = accO[ot][mt][r];
      }
    }
  }
}

// ---------------- K3: out = part0 + part1 + bg ----------------
__global__ __launch_bounds__(256) void combine(const float* __restrict__ part,
                                               const float* __restrict__ bg,
                                               float* __restrict__ out) {
  // grid 4096 x 256; 4 floats/thread. i covers [B][C][N]; o = (i>>12)&255.
  size_t i = ((size_t)blockIdx.x * 256 + threadIdx.x) * 4;
  float4v p0 = *(const float4v*)(part + i);
  float4v p1 = *(const float4v*)(part + (size_t)B_ * C_ * N_ + i);
  float bgo = bg[(i >> 12) & 255];
  float4v r = p0 + p1;
  r[0] += bgo; r[1] += bgo; r[2] += bgo; r[3] += bgo;
  *(float4v*)(out + i) = r;
}

extern "C" void kernel_launch(void* const* d_in, const int* in_sizes, int n_in,
                              void* d_out, int out_size, void* d_ws, size_t ws_size,
                              hipStream_t stream) {
  const float* x = (const float*)d_in[0];
  const float* wq = (const float*)d_in[1];
  const float* bq = (const float*)d_in[2];
  const float* wk = (const float*)d_in[3];
  const float* bk = (const float*)d_in[4];
  const float* wv = (const float*)d_in[5];
  const float* bv = (const float*)d_in[6];
  const float* wg = (const float*)d_in[7];
  const float* bg = (const float*)d_in[8];
  float* out = (float*)d_out;

  char* ws = (char*)d_ws;
  f16* QTt = (f16*)ws; ws += (size_t)B_ * N_ * CQK * sizeof(f16);   // 2.1 MB
  f16* KTt = (f16*)ws; ws += (size_t)B_ * N_ * CQK * sizeof(f16);   // 2.1 MB
  f16* Vt  = (f16*)ws; ws += (size_t)B_ * C_ * N_ * sizeof(f16);    // 8.4 MB
  f16* WQt = (f16*)ws; ws += (size_t)CQK * C_ * sizeof(f16);
  f16* WKt = (f16*)ws; ws += (size_t)CQK * C_ * sizeof(f16);
  f16* WVt = (f16*)ws; ws += (size_t)C_ * C_ * sizeof(f16);
  f16* WGt = (f16*)ws; ws += (size_t)C_ * C_ * sizeof(f16);
  float* PART = (float*)ws; ws += (size_t)SEG * B_ * C_ * N_ * sizeof(float);  // 33.6 MB

  prep_w<<<dim3(80), 256, 0, stream>>>(wq, wk, wv, wg, WQt, WKt, WVt, WGt);
  proj<<<dim3(N_ / 64, B_), 512, 0, stream>>>(x, WQt, WKt, WVt, bq, bk, bv,
                                              QTt, KTt, Vt);
  attn<<<dim3(N_ / 64, SEG, B_), 256, 0, stream>>>(QTt, KTt, Vt, WGt, PART);
  combine<<<dim3(4096), 256, 0, stream>>>(PART, bg, out);
}